// Round 1
// 105.878 us; speedup vs baseline: 1.0373x; 1.0373x over previous
//
#include <hip/hip_runtime.h>

// Problem constants
#define H_ 96
#define W_ 96
#define HW 9216        // 96*96
#define C_ 64
#define OUTC 64
#define NPTS 9
#define NCH 18
#define B_ 8

// LDS patch: 8 rows x 20 cols x 64 ch (padded to 72 shorts) per 4-row x 16-col tile
#define PCH 72

typedef __attribute__((ext_vector_type(8))) short short8;   // 8 bf16
typedef __attribute__((ext_vector_type(4))) float f32x4;
typedef __attribute__((ext_vector_type(4))) unsigned int uint4v;

__device__ __forceinline__ short f2bf(float f) {
    union { float f; unsigned u; } v; v.f = f;
    unsigned r = v.u + 0x7fffu + ((v.u >> 16) & 1u);   // RNE
    return (short)(r >> 16);
}
__device__ __forceinline__ float bflo(unsigned d) {
    union { unsigned u; float f; } v; v.u = d << 16; return v.f;
}
__device__ __forceinline__ float bfhi(unsigned d) {
    union { unsigned u; float f; } v; v.u = d & 0xffff0000u; return v.f;
}

// ---------------- Kernel 1: transpose (4px x 8ch per thread, float4 reads) + weight prep ----------------
__global__ __launch_bounds__(256) void prep_xpose(
    const float* __restrict__ x, const float* __restrict__ w_ker,
    const float* __restrict__ w_off, short* __restrict__ x_t,
    short* __restrict__ wk_frag, short* __restrict__ woff_frag)
{
    int blk = blockIdx.x;
    int t   = threadIdx.x;
    if (blk < 576) {
        int b   = blk & 7;               // image -> XCD pin
        int sub = blk >> 3;              // 0..71 -> 128 px per block
        int cb  = t & 7;                 // 8-channel block
        int px  = sub * 128 + (t >> 3) * 4;

        const float* xp = x + ((size_t)(b * C_ + cb * 8) * HW) + px;
        f32x4 tl[8];
#pragma unroll
        for (int e = 0; e < 8; ++e) tl[e] = *(const f32x4*)(xp + (size_t)e * HW);
#pragma unroll
        for (int p = 0; p < 4; ++p) {
            short8 s;
#pragma unroll
            for (int e = 0; e < 8; ++e) s[e] = f2bf(tl[e][p]);
            *(short8*)(x_t + ((size_t)(b * HW + px + p) * 64) + cb * 8) = s;
        }
    } else {
        int idx = (blk - 576) * 256 + t;            // 0..55295
        if (idx < 36864) {                          // wk_frag: NT=4
            int j = idx & 7, l = (idx >> 3) & 63, nt = (idx >> 9) & 3, sg = idx >> 11;
            int q2 = sg & 1, n = sg >> 1;
            int c  = q2 * 32 + ((l >> 4) << 3) + j;
            int oc = nt * 16 + (l & 15);
            wk_frag[idx] = f2bf(w_ker[(oc * C_ + c) * 9 + n]);
        } else {                                    // woff_frag: NT=2 (18 padded to 32)
            int k = idx - 36864;                    // 0..18431
            int j = k & 7, l = (k >> 3) & 63, nt = (k >> 9) & 1, sg = k >> 10;
            int q2 = sg & 1, n = sg >> 1;
            int c  = q2 * 32 + ((l >> 4) << 3) + j;
            int oc = nt * 16 + (l & 15);
            woff_frag[k] = (oc < NCH) ? f2bf(w_off[(oc * C_ + c) * 9 + n]) : (short)0;
        }
    }
}

// ---------------- Kernel 2: fused offset-conv + deformable sample + GEMM ----------------
// Block = 256 thr (4 waves) = 4 pixel-rows x 16 cols. Each wave owns ONE pixel
// row and runs ALL 9 taps of both phases for it: no cross-wave reduction, no
// tap imbalance, only 2 block barriers (after patch stage; before LDS reuse in
// the epilogue). Phase-1 offsets go through a per-wave LDS table (wave-local,
// no barrier). Epilogue transposes each wave's 16px x 64oc tile through its own
// quarter of the (reused) patch LDS for coalesced 64B stores.
__global__ __launch_bounds__(256, 5) void deform_fused(
    const short* __restrict__ x_t, const short* __restrict__ woff_frag,
    const float* __restrict__ b_off, const short* __restrict__ wk_frag,
    const float* __restrict__ b_ker, float* __restrict__ out)
{
    __shared__ __align__(16) short sX[160 * PCH];   // 23040 B: [r*20+c][ch(72)]; reused as float sF[4][64][20] in epilogue
    __shared__ float2 sP[4][16][9];                 // 4608 B: per-wave per-pixel (ox,oy) per tap

    int t    = threadIdx.x;
    int lane = t & 63;
    int wv   = t >> 6;                  // 0..3 = pixel row within tile
    int b    = blockIdx.x & 7;          // image -> XCD pin
    int s    = blockIdx.x >> 3;         // 0..143
    int rg   = s / 6;                   // row group: i0 = rg*4
    int cs   = s - rg * 6;              // col strip: j0 = cs*16
    int i0   = rg * 4;
    int j0   = cs * 16;
    int pxl  = lane & 15, kq = lane >> 4;
    int iw   = i0 + wv;                 // this wave's pixel row
    int j    = j0 + pxl;
    const short* xb = x_t + (size_t)b * HW * 64;
    const short8 Z8 = {0,0,0,0,0,0,0,0};

    // ---- stage the 8x20 patch (rows i0-2..i0+5, cols j0-2..j0+17; clamped source) ----
#pragma unroll
    for (int k = 0; k < 5; ++k) {
        int u  = t + k * 256;                // 1280 units = 160 rc x 8 cb
        int cb = u & 7, rc = u >> 3;
        int r = rc / 20, c = rc - r * 20;
        int row = min(max(i0 - 2 + r, 0), H_ - 1);
        int col = min(max(j0 - 2 + c, 0), W_ - 1);
        *(short8*)&sX[rc * PCH + cb * 8] =
            *(const short8*)(xb + (row * W_ + col) * 64 + cb * 8);
    }
    __syncthreads();

    // ---- phase 1: offset conv, all 9 taps, wave-local accumulation ----
    f32x4 pa0 = {0,0,0,0}, pa1 = {0,0,0,0};
#pragma unroll
    for (int n = 0; n < 9; ++n) {
        int di = n / 3 - 1, dj = n % 3 - 1;
        bool ok = ((unsigned)(iw + di) < (unsigned)H_) & ((unsigned)(j + dj) < (unsigned)W_);
        int rcb = ((wv + di + 2) * 20 + (pxl + dj + 2)) * PCH;
#pragma unroll
        for (int q2 = 0; q2 < 2; ++q2) {
            short8 a = *(const short8*)&sX[rcb + q2 * 32 + kq * 8];
            a = ok ? a : Z8;
            const short* wb = woff_frag + ((n * 2 + q2) * 2) * 512 + lane * 8;
            short8 b0 = *(const short8*)(wb);
            short8 b1 = *(const short8*)(wb + 512);
            pa0 = __builtin_amdgcn_mfma_f32_16x16x32_bf16(a, b0, pa0, 0, 0, 0);
            pa1 = __builtin_amdgcn_mfma_f32_16x16x32_bf16(a, b1, pa1, 0, 0, 0);
        }
    }
    {   // C/D: col=lane&15 (=offset ch), row=(lane>>4)*4+r (=px). Wave-local table.
        int col = lane & 15, rq = lane >> 4;
        float bo = b_off[col];
        if (col < 9) {
#pragma unroll
            for (int r = 0; r < 4; ++r) sP[wv][rq * 4 + r][col].x = pa0[r] + bo;
        } else {
#pragma unroll
            for (int r = 0; r < 4; ++r) sP[wv][rq * 4 + r][col - 9].y = pa0[r] + bo;
        }
        if (col < 2) {
            float bo2 = b_off[16 + col];
#pragma unroll
            for (int r = 0; r < 4; ++r) sP[wv][rq * 4 + r][7 + col].y = pa1[r] + bo2;
        }
    }
    // same-wave produce->consume through LDS: lgkmcnt ordering suffices, no barrier

    // ---- phase 2: sample (LDS patch, global fallback) + GEMM, all 9 taps ----
    f32x4 acc[4];
#pragma unroll
    for (int nt = 0; nt < 4; ++nt) acc[nt] = (f32x4){0.f, 0.f, 0.f, 0.f};

#pragma unroll
    for (int n = 0; n < 9; ++n) {
        int di = n / 3 - 1, dj = n % 3 - 1;
        float2 o = sP[wv][pxl][n];
        float fpx = (float)(iw + di) + o.x;
        float fpy = (float)(j + dj) + o.y;
        float x0f = floorf(fpx), y0f = floorf(fpy);
        float lx = fpx - x0f, ly = fpy - y0f;
        int xi = (int)x0f, yi = (int)y0f;
        float wx0 = (xi >= 0  && xi <= H_ - 1) ? (1.0f - lx) : 0.0f;
        float wx1 = (xi >= -1 && xi <= H_ - 2) ? lx          : 0.0f;
        float wy0 = (yi >= 0  && yi <= W_ - 1) ? (1.0f - ly) : 0.0f;
        float wy1 = (yi >= -1 && yi <= W_ - 2) ? ly          : 0.0f;
        float w00 = wx0 * wy0, w10 = wx1 * wy0, w01 = wx0 * wy1, w11 = wx1 * wy1;
        int rp = xi - (i0 - 2), cp = yi - (j0 - 2);
        bool inp = (rp >= 0) & (rp <= 6) & (cp >= 0) & (cp <= 18);
        uint4v u[8];
        if (inp) {   // common path: patch reads (content is clamp-equivalent)
            int l00 = (rp * 20 + cp) * PCH;
            int l10 = l00 + 20 * PCH, l01 = l00 + PCH, l11 = l10 + PCH;
#pragma unroll
            for (int q2 = 0; q2 < 2; ++q2) {
                int cho = q2 * 32 + kq * 8;
                u[q2*4+0] = *(const uint4v*)&sX[l00 + cho];
                u[q2*4+1] = *(const uint4v*)&sX[l10 + cho];
                u[q2*4+2] = *(const uint4v*)&sX[l01 + cho];
                u[q2*4+3] = *(const uint4v*)&sX[l11 + cho];
            }
        }
        if (!inp) {  // rare: |offset| >= 1 -> direct global gather from x_t
            int r0 = min(max(xi,     0), H_ - 1) * W_;
            int r1 = min(max(xi + 1, 0), H_ - 1) * W_;
            int c0 = min(max(yi,     0), W_ - 1);
            int c1 = min(max(yi + 1, 0), W_ - 1);
#pragma unroll
            for (int q2 = 0; q2 < 2; ++q2) {
                int cho = q2 * 32 + kq * 8;
                u[q2*4+0] = *(const uint4v*)(xb + (r0 + c0) * 64 + cho);
                u[q2*4+1] = *(const uint4v*)(xb + (r1 + c0) * 64 + cho);
                u[q2*4+2] = *(const uint4v*)(xb + (r0 + c1) * 64 + cho);
                u[q2*4+3] = *(const uint4v*)(xb + (r1 + c1) * 64 + cho);
            }
        }
#pragma unroll
        for (int q2 = 0; q2 < 2; ++q2) {
            short8 A;
#pragma unroll
            for (int d = 0; d < 4; ++d) {
                float lo = w00 * bflo(u[q2*4+0][d]) + w10 * bflo(u[q2*4+1][d])
                         + w01 * bflo(u[q2*4+2][d]) + w11 * bflo(u[q2*4+3][d]);
                float hi = w00 * bfhi(u[q2*4+0][d]) + w10 * bfhi(u[q2*4+1][d])
                         + w01 * bfhi(u[q2*4+2][d]) + w11 * bfhi(u[q2*4+3][d]);
                A[2 * d]     = f2bf(lo);
                A[2 * d + 1] = f2bf(hi);
            }
            const short* wbp = wk_frag + ((n * 2 + q2) * 4) * 512 + lane * 8;
#pragma unroll
            for (int nt = 0; nt < 4; ++nt) {
                short8 bfr = *(const short8*)(wbp + nt * 512);
                acc[nt] = __builtin_amdgcn_mfma_f32_16x16x32_bf16(A, bfr, acc[nt], 0, 0, 0);
            }
        }
    }

    // ---- epilogue: per-wave transpose through own LDS quarter, coalesced stores ----
    __syncthreads();                       // all waves done reading sX patch
    float* fw = (float*)sX + wv * 1280;    // 64 oc x 20 (padded) floats per wave
    {
        int col = lane & 15, rq = lane >> 4;
#pragma unroll
        for (int nt = 0; nt < 4; ++nt) {
            int oc = nt * 16 + col;
            float bias = b_ker[oc];
#pragma unroll
            for (int r = 0; r < 4; ++r)
                fw[oc * 20 + rq * 4 + r] = acc[nt][r] + bias;
        }
    }
    // wave-local write->read: no barrier needed
    {
        int ocl = lane >> 2, qq = lane & 3;
        float* ob = out + (size_t)b * OUTC * HW + iw * W_ + j0 + qq * 4;
#pragma unroll
        for (int it = 0; it < 4; ++it) {
            int oc = it * 16 + ocl;
            f32x4 v = *(const f32x4*)&fw[oc * 20 + qq * 4];
            *(f32x4*)(ob + (size_t)oc * HW) = v;
        }
    }
}

extern "C" void kernel_launch(void* const* d_in, const int* in_sizes, int n_in,
                              void* d_out, int out_size, void* d_ws, size_t ws_size,
                              hipStream_t stream) {
    const float* x     = (const float*)d_in[0];
    const float* w_off = (const float*)d_in[1];
    const float* b_off = (const float*)d_in[2];
    const float* w_ker = (const float*)d_in[3];
    const float* b_ker = (const float*)d_in[4];
    float* out = (float*)d_out;

    // workspace: x_t 9,437,184 B | wk_frag 73,728 B | woff_frag 36,864 B
    char*  wsb       = (char*)d_ws;
    short* x_t       = (short*)wsb;
    short* wk_frag   = (short*)(wsb + 9437184);
    short* woff_frag = wk_frag + 36864;

    prep_xpose  <<<792,  256, 0, stream>>>(x, w_ker, w_off, x_t, wk_frag, woff_frag);
    deform_fused<<<1152, 256, 0, stream>>>(x_t, woff_frag, b_off, wk_frag, b_ker, out);
}